// Round 1
// 373.077 us; speedup vs baseline: 1.0091x; 1.0091x over previous
//
#include <hip/hip_runtime.h>

// Morphological skeleton, 16 x 1024 x 1024 f32.
// skel = sum_{k=0..20} ( e_k - dilate3x3(e_{k+1}) ),  e_0 = x, e_{k+1} = erode3x3(e_k)
// (reduce_window SAME semantics: windows clamp at image borders).
//
// Register-resident vertical pipeline, zero LDS tile. 3 dispatches x G=7 fused
// erosion stages. One wave (64 lanes x float4) owns a 256-col band and sweeps
// RCH+16 rows (RCH output + warm-up/drain). Per stage: 2-row register buffer
// (parity-swapped); erode = v_min3 vertical + shfl lane+-1 horizontal; dilate
// of f_{s+1} reuses stage s+1's buffers (read before their update); terms go
// into an 8-deep register FIFO, emitted as rows complete.
//
// Round-5 change vs round 4 (376 us): occupancy. 5x16x16 = 1280 single-wave
// blocks on 1024 SIMDs = 1.25 waves/SIMD; the per-stage dependent chain
// (min3 -> ds_bpermute -> min3) can't exceed ~40% VALU duty with one wave
// (measured VALUBusy 40.8, Occupancy 11.7). RCH 64->32 doubles the grid to
// 2560 waves (~2.5/SIMD; VGPR=108 allows 4) at +20% warm-up work.
//
// Correctness invariants (desk-verified):
//  - y0 = 32k keeps t0 = y0-8 even -> parity mapping of pf/skpf slots holds.
//  - synthetic erode values at OOB/warm-up rows are >= the true clamped
//    erosion (dependency-cone subset) => harmless in the min chain; masked to
//    -BIG in the dilate max via wave-uniform row conditionals (topOK/botOK).
//  - halos exactly tight: 8 rows warm-up (t0 = y0-8), 8 cols/side shrink;
//    bands own disjoint column ranges {[0,248),[248,488),[488,728),[728,968),
//    [968,1024)} so the skel read-modify-write never races.

static constexpr int W = 1024, H = 1024, NIMG = 16;
static constexpr int RCH = 32;           // output rows per wave
static constexpr int NSTEP = RCH + 16;   // sweep steps (8 warm-up + 8 drain)
static constexpr float BIG = 3.0e38f;

__device__ __forceinline__ float min3f(float a, float b, float c) { return fminf(fminf(a, b), c); }
__device__ __forceinline__ float max3f(float a, float b, float c) { return fmaxf(fmaxf(a, b), c); }

template<bool FIRST, bool WRITE_E, int PFI>
__device__ __forceinline__
void pipe_step(int t, int y0, int lane, int gx,
               bool leftEdge, bool rightEdge, bool lane_ok,
               const float* __restrict__ in, float* __restrict__ eo,
               float* __restrict__ sk,
               float4 (&OB)[7], float4 (&MB)[7], float4& OD, float4& MD,
               float4 (&acc)[8], float4 (&pf)[2], float4 (&skpf)[2])
{
    // consume input row t (OOB rows are +BIG: erode identity)
    float4 cur;
    if ((unsigned)t < (unsigned)H) cur = pf[PFI];
    else                           cur = make_float4(BIG, BIG, BIG, BIG);
    // prefetch input row t+2 into the slot just consumed
    {
        const int nr = t + 2;
        if ((unsigned)nr < (unsigned)H && nr <= y0 + RCH + 7)
            pf[PFI] = *(const float4*)&in[(size_t)nr * W + gx];
    }

#pragma unroll
    for (int s = 0; s < 7; ++s) {
        // invariant at entry: OB[s] = f_s(t-s-2), MB[s] = f_s(t-s-1),
        // cur = f_s(t-s) (produced this step by the previous stage / load).
        const float4 fOld = OB[s];
        const float4 fMid = MB[s];

        // ---- erode: en = f_{s+1}(t-s-1) ----
        float4 vm;
        vm.x = min3f(fOld.x, fMid.x, cur.x);
        vm.y = min3f(fOld.y, fMid.y, cur.y);
        vm.z = min3f(fOld.z, fMid.z, cur.z);
        vm.w = min3f(fOld.w, fMid.w, cur.w);
        float lft = __shfl(vm.w, lane - 1);   // lane 0: garbage -> invalid cols
        float rgt = __shfl(vm.x, lane + 1);   // lane 63: garbage -> invalid cols
        if (leftEdge)  lft = BIG;             // true image border clamp
        if (rightEdge) rgt = BIG;
        float4 en;
        en.x = min3f(lft,  vm.x, vm.y);
        en.y = min3f(vm.x, vm.y, vm.z);
        en.z = min3f(vm.y, vm.z, vm.w);
        en.w = min3f(vm.z, vm.w, rgt);

        OB[s] = cur;   // old-role slot receives newest f_s row (parity swap)

        // ---- dilate of f_{s+1} centered at row t-s-2 ----
        // gOld/gMid from stage s+1's buffers, read BEFORE their update in
        // iteration s+1 of this same step.
        float4 gOld, gMid;
        if (s < 6) { gOld = OB[s + 1]; gMid = MB[s + 1]; }  // f_{s+1}(t-s-3), (t-s-2)
        else       { gOld = OD;        gMid = MD;        }
        const bool topOK = (t - s - 3) >= 0;   // row t-s-3 in-image?
        const bool botOK = (t - s - 1) < H;    // row t-s-1 in-image?
        float4 vx;
        {
            float txx = topOK ? gOld.x : -BIG, bxx = botOK ? en.x : -BIG;
            float txy = topOK ? gOld.y : -BIG, bxy = botOK ? en.y : -BIG;
            float txz = topOK ? gOld.z : -BIG, bxz = botOK ? en.z : -BIG;
            float txw = topOK ? gOld.w : -BIG, bxw = botOK ? en.w : -BIG;
            vx.x = max3f(txx, gMid.x, bxx);
            vx.y = max3f(txy, gMid.y, bxy);
            vx.z = max3f(txz, gMid.z, bxz);
            vx.w = max3f(txw, gMid.w, bxw);
        }
        float dl = __shfl(vx.w, lane - 1);
        float dr = __shfl(vx.x, lane + 1);
        if (leftEdge)  dl = -BIG;
        if (rightEdge) dr = -BIG;
        float4 dn;
        dn.x = max3f(dl,   vx.x, vx.y);
        dn.y = max3f(vx.x, vx.y, vx.z);
        dn.z = max3f(vx.y, vx.z, vx.w);
        dn.w = max3f(vx.z, vx.w, dr);

        // term_s(t-s-2) = f_s(t-s-2) - dilate(f_{s+1})(t-s-2); FIFO slot 6-s
        acc[6 - s].x += fOld.x - dn.x;
        acc[6 - s].y += fOld.y - dn.y;
        acc[6 - s].z += fOld.z - dn.z;
        acc[6 - s].w += fOld.w - dn.w;

        if (s == 6) {
            if (WRITE_E) {
                const int er = t - 7;          // en = f_7(t-7)
                if (er >= y0 && er < y0 + RCH && lane_ok)
                    *(float4*)&eo[(size_t)er * W + gx] = en;
            }
            OD = en;
        }
        cur = en;   // becomes f_{s+1}(t-(s+1)) for the next stage
    }

    // ---- emit completed row t-8 ----
    if (t >= y0 + 8) {
        const int r = t - 8;
        float4 v = acc[0];
        if (!FIRST) {
            const float4 o = skpf[PFI];        // skel row t-8, prefetched at step t-2
            v.x += o.x; v.y += o.y; v.z += o.z; v.w += o.w;
        }
        if (lane_ok)
            *(float4*)&sk[(size_t)r * W + gx] = v;
    }
#pragma unroll
    for (int j = 0; j < 7; ++j) acc[j] = acc[j + 1];
    acc[7] = make_float4(0.f, 0.f, 0.f, 0.f);

    // ---- prefetch old skel row t-6 AFTER emission (consumed at step t+2,
    //      which shares this step's parity and thus this PFI slot) ----
    if (!FIRST) {
        const int pr = t - 6;
        if (pr >= y0 && pr < y0 + RCH)
            skpf[PFI] = *(const float4*)&sk[(size_t)pr * W + gx];
    }
}

template<bool FIRST, bool WRITE_E>
__global__ __launch_bounds__(64)
void skel_pipe(const float* __restrict__ ein, float* __restrict__ eout,
               float* __restrict__ skel)
{
    const int lane = threadIdx.x;          // one wave per block
    const int bx = blockIdx.x;             // band 0..4
    const int y0 = blockIdx.y * RCH;       // row chunk
    const int img = blockIdx.z;
    const int x0 = (bx == 4) ? 768 : bx * 240;   // last band starts at 1024-256
    const int gx = x0 + 4 * lane;                // gx max = 768 + 252 = 1020

    const size_t base = (size_t)img * (size_t)(W * H);
    const float* __restrict__ in = ein + base;
    float* __restrict__ eo = eout + base;
    float* __restrict__ sk = skel + base;

    const bool leftEdge  = (gx == 0);
    const bool rightEdge = (gx + 4 == W);
    // disjoint write ownership (bands overlap in compute, never in writes)
    const int own_lo = (bx == 0) ? 0 : ((bx == 4) ? 968 : x0 + 8);
    const int own_hi = (bx == 4) ? W : x0 + 248;
    const bool lane_ok = (gx >= own_lo) && (gx < own_hi);

    float4 B0[7], B1[7], D0, D1, acc[8], pf[2], skpf[2];
    const float4 big4 = make_float4(BIG, BIG, BIG, BIG);
    const float4 z4   = make_float4(0.f, 0.f, 0.f, 0.f);
#pragma unroll
    for (int s = 0; s < 7; ++s) { B0[s] = big4; B1[s] = big4; }
    D0 = big4; D1 = big4;
#pragma unroll
    for (int j = 0; j < 8; ++j) acc[j] = z4;
    pf[0] = big4; pf[1] = big4; skpf[0] = z4; skpf[1] = z4;

    // prefetch input rows t0, t0+1
    {
        const int r0 = y0 - 8, r1 = y0 - 7;
        if (r0 >= 0) pf[0] = *(const float4*)&in[(size_t)r0 * W + gx];
        if (r1 >= 0) pf[1] = *(const float4*)&in[(size_t)r1 * W + gx];
    }

    const int t0 = y0 - 8;   // even (y0 multiple of 32) -> parity mapping holds
#pragma unroll 1
    for (int t = t0; t < t0 + NSTEP; t += 2) {
        pipe_step<FIRST, WRITE_E, 0>(t,     y0, lane, gx, leftEdge, rightEdge, lane_ok,
                                     in, eo, sk, B0, B1, D0, D1, acc, pf, skpf);
        pipe_step<FIRST, WRITE_E, 1>(t + 1, y0, lane, gx, leftEdge, rightEdge, lane_ok,
                                     in, eo, sk, B1, B0, D1, D0, acc, pf, skpf);
    }
}

extern "C" void kernel_launch(void* const* d_in, const int* in_sizes, int n_in,
                              void* d_out, int out_size, void* d_ws, size_t ws_size,
                              hipStream_t stream)
{
    const float* x = (const float*)d_in[0];
    float* skel = (float*)d_out;
    const size_t n = (size_t)NIMG * W * H;

    float* e0 = (float*)d_ws;
    float* e1 = e0 + n;

    dim3 grid(5, H / RCH, NIMG);
    dim3 block(64);

    // steps 0-6: x -> e0 ; 7-13: e0 -> e1 ; 14-20: e1 -> (none)
    skel_pipe<true,  true ><<<grid, block, 0, stream>>>(x,  e0, skel);
    skel_pipe<false, true ><<<grid, block, 0, stream>>>(e0, e1, skel);
    skel_pipe<false, false><<<grid, block, 0, stream>>>(e1, e0, skel);
}